// Round 6
// baseline (28.557 us; speedup 1.0000x reference)
//
#include <hip/hip_runtime.h>
#include <stdint.h>

#define BATCH 2048
#define NPS 8
#define DFEAT 256

// Constant-address-space float: forces s_load (SMEM) codegen for uniform reads.
typedef const float __attribute__((address_space(4))) cfp;

// DIAGNOSTIC ROUND: identical round-5 kernel, launched TWICE back-to-back.
// Slope (dur_r6 - dur_r5) = true warm kernel time; separates fixed replay
// overhead from kernel-body time. Second launch is idempotent and correct.
__global__ __launch_bounds__(512) void ppdet_kernel(
    const float* __restrict__ eq,      // (B, 16, 256)
    const float* __restrict__ r_ei,    // (B, 16, 4, 3)
    const float* __restrict__ W,       // (2, 512, 8)
    const float* __restrict__ bias,    // (2, 8)
    const float* __restrict__ env_dim, // (2, 8, 4, 3, 3)
    const float* __restrict__ env_ion, // (2, 4, 8)
    float* __restrict__ out)           // (2, 2048, 8)
{
    __shared__ __align__(16) float part[8 * 64 * 16]; // 32 KB, XOR-swizzled slots
    __shared__ __align__(16) float AB[64 * 16];       // [row][k<8:A+bias, k>=8:Bt]
    __shared__ __align__(16) float envl[512];         // [w][j][k]

    const int tid = threadIdx.x;
    const int bid = blockIdx.x;
    const int s  = bid & 1;
    const int b0 = (bid >> 1) * 8;

    const int wq   = __builtin_amdgcn_readfirstlane(tid >> 6); // 0..7, uniform
    const int lane = tid & 63;
    const int wl   = lane >> 3, ii = lane & 7;

    cfp* wb1 = (cfp*)(uintptr_t)(W + s * 4096 + wq * 256);
    const size_t grow = (size_t)(b0 + wl) * 16 + s * 8 + ii;
    const float* xrow = eq + grow * DFEAT + wq * 32;

    float4 xv[8];
#pragma unroll
    for (int u = 0; u < 8; ++u) xv[u] = ((const float4*)xrow)[u];

    float acc[16];
#pragma unroll
    for (int k = 0; k < 16; ++k) acc[k] = 0.f;

#pragma unroll
    for (int u = 0; u < 8; ++u) {
        cfp* wr = wb1 + u * 32;
        float xs0 = xv[u].x, xs1 = xv[u].y, xs2 = xv[u].z, xs3 = xv[u].w;
#pragma unroll
        for (int c = 0; c < 4; ++c) {
            float xc = (c == 0) ? xs0 : (c == 1) ? xs1 : (c == 2) ? xs2 : xs3;
#pragma unroll
            for (int k = 0; k < 8; ++k) {
                acc[k]     = fmaf(xc, wr[c * 8 + k],        acc[k]);
                acc[8 + k] = fmaf(xc, wr[2048 + c * 8 + k], acc[8 + k]);
            }
        }
    }

    {
        float* pb = part + (wq * 64 + lane) * 16;
        const int sw = (lane >> 1) & 3;
#pragma unroll
        for (int kg = 0; kg < 4; ++kg) {
            int slot = kg ^ sw;
            float4 v = make_float4(acc[kg * 4], acc[kg * 4 + 1],
                                   acc[kg * 4 + 2], acc[kg * 4 + 3]);
            *(float4*)(pb + slot * 4) = v;
        }
    }

    {
        const int w = tid >> 6, k = (tid >> 3) & 7, j = tid & 7;
        const size_t rrow = ((size_t)(b0 + w) * 16 + s * 8 + j) * 12;
        const float4* rp = (const float4*)(r_ei + rrow);
        float4 ra = rp[0], rb = rp[1], rc = rp[2];
        float rr[12] = {ra.x, ra.y, ra.z, ra.w, rb.x, rb.y, rb.z, rb.w,
                        rc.x, rc.y, rc.z, rc.w};
        float e = 0.f;
#pragma unroll
        for (int a = 0; a < 4; ++a) {
            const float* Md = env_dim + ((size_t)(s * 8 + k) * 4 + a) * 9;
            float r0 = rr[a * 3], r1 = rr[a * 3 + 1], r2 = rr[a * 3 + 2];
            float e0 = r0 * Md[0] + r1 * Md[3] + r2 * Md[6];
            float e1 = r0 * Md[1] + r1 * Md[4] + r2 * Md[7];
            float e2 = r0 * Md[2] + r1 * Md[5] + r2 * Md[8];
            float dist = sqrtf(e0 * e0 + e1 * e1 + e2 * e2);
            e = fmaf(env_ion[(s * 4 + a) * 8 + k], __expf(-dist), e);
        }
        envl[w * 64 + j * 8 + k] = e;
    }

    __syncthreads();

    if (tid < 256) {
        const int row = tid >> 2, sl = tid & 3;
        const int g = sl ^ ((row >> 1) & 3);
        float4 sum = make_float4(0.f, 0.f, 0.f, 0.f);
#pragma unroll
        for (int q2 = 0; q2 < 8; ++q2) {
            float4 v = *(const float4*)(part + (q2 * 64 + row) * 16 + sl * 4);
            sum.x += v.x; sum.y += v.y; sum.z += v.z; sum.w += v.w;
        }
        if (g < 2) {
            sum.x += bias[s * 8 + g * 4];
            sum.y += bias[s * 8 + g * 4 + 1];
            sum.z += bias[s * 8 + g * 4 + 2];
            sum.w += bias[s * 8 + g * 4 + 3];
        }
        *(float4*)(AB + row * 16 + g * 4) = sum;
    }

    __syncthreads();

    if (tid < 64) {
        const int w = tid >> 3, i = tid & 7;
        float Arow[8];
#pragma unroll
        for (int k = 0; k < 8; ++k) Arow[k] = AB[(w * 8 + i) * 16 + k];
        float M[8][8];
#pragma unroll
        for (int j = 0; j < 8; ++j) {
#pragma unroll
            for (int k = 0; k < 8; ++k)
                M[j][k] = (Arow[k] + AB[(w * 8 + j) * 16 + 8 + k])
                          * envl[w * 64 + j * 8 + k];
        }
        float det = 1.f;
#pragma unroll
        for (int p = 0; p < 8; ++p) {
            int piv = p;
            float mx = fabsf(M[p][p]);
#pragma unroll
            for (int r2 = p + 1; r2 < 8; ++r2) {
                float v = fabsf(M[r2][p]);
                if (v > mx) { mx = v; piv = r2; }
            }
#pragma unroll
            for (int r2 = p + 1; r2 < 8; ++r2) {
                bool sw = (piv == r2);
#pragma unroll
                for (int c = p; c < 8; ++c) {
                    float a = M[p][c], bb = M[r2][c];
                    M[p][c]  = sw ? bb : a;
                    M[r2][c] = sw ? a : bb;
                }
            }
            det = (piv != p) ? -det : det;
            float d = M[p][p];
            det *= d;
            float inv = (d != 0.f) ? 1.f / d : 0.f;
#pragma unroll
            for (int r2 = p + 1; r2 < 8; ++r2) {
                float fct = M[r2][p] * inv;
#pragma unroll
                for (int c = p + 1; c < 8; ++c) M[r2][c] -= fct * M[p][c];
            }
        }
        out[(size_t)s * (BATCH * NPS) + (size_t)(b0 + w) * NPS + i] = det;
    }
}

extern "C" void kernel_launch(void* const* d_in, const int* in_sizes, int n_in,
                              void* d_out, int out_size, void* d_ws, size_t ws_size,
                              hipStream_t stream) {
    const float* eq      = (const float*)d_in[0];
    const float* r_ei    = (const float*)d_in[1];
    const float* W       = (const float*)d_in[2];
    const float* bias    = (const float*)d_in[3];
    const float* env_dim = (const float*)d_in[4];
    const float* env_ion = (const float*)d_in[5];
    float* out = (float*)d_out;

    // Diagnostic double-launch: slope vs round 5 = true warm kernel time.
    ppdet_kernel<<<512, 512, 0, stream>>>(eq, r_ei, W, bias, env_dim, env_ion, out);
    ppdet_kernel<<<512, 512, 0, stream>>>(eq, r_ei, W, bias, env_dim, env_ion, out);
}

// Round 7
// 15.522 us; speedup vs baseline: 1.8398x; 1.8398x over previous
//
#include <hip/hip_runtime.h>
#include <stdint.h>

#define BATCH 2048
#define NPS 8
#define DFEAT 256

// Constant-address-space float: forces s_load (SMEM) codegen for uniform reads.
typedef const float __attribute__((address_space(4))) cfp;
// Address-space pointers for global_load_lds (CK-style incantation).
typedef __attribute__((address_space(3))) uint32_t lds_u32;
typedef const __attribute__((address_space(1))) uint32_t glb_u32;

// Block: 512 threads = 8 waves, 8 walkers x 1 spin (64 rows, 64 dets).
// Phase 0: wave wq stages rows [wq*8, wq*8+8) straight into LDS via
//          global_load_lds (coalesced 1KB/inst). Swizzle is applied on the
//          per-lane GLOBAL source (lane^u) so LDS dest stays linear (m104):
//          X[r][p16] = x[r][p16 ^ (r&7)] at 16B granularity.
// Phase 1: lane = row; 8x ds_read_b128 at chunk^(r&7) (b128 bank floor),
//          512 fmac vs scalar-loaded W (addrspace(4)).
// Phase 2: part-reduce -> AB, envelope, serial in-register LU (tid<64).
__global__ __launch_bounds__(512) void ppdet_kernel(
    const float* __restrict__ eq,      // (B, 16, 256)
    const float* __restrict__ r_ei,    // (B, 16, 4, 3)
    const float* __restrict__ W,       // (2, 512, 8)
    const float* __restrict__ bias,    // (2, 8)
    const float* __restrict__ env_dim, // (2, 8, 4, 3, 3)
    const float* __restrict__ env_ion, // (2, 4, 8)
    float* __restrict__ out)           // (2, 2048, 8)
{
    __shared__ __align__(16) float X[64 * DFEAT]; // 64KB x-tile; part aliases 1st 32KB
    __shared__ __align__(16) float AB[64 * 16];   // [row][k<8:A+bias, k>=8:Bt]
    __shared__ __align__(16) float envl[512];     // [w][j][k]
    float* part = X;                              // 8*64*16 floats, reused after GEMM

    const int tid = threadIdx.x;
    const int bid = blockIdx.x;
    const int s  = bid & 1;
    const int b0 = (bid >> 1) * 8;

    const int wq   = __builtin_amdgcn_readfirstlane(tid >> 6); // 0..7, uniform
    const int lane = tid & 63;

    // ---- Phase 0a: direct-to-LDS staging, swizzled global source
    {
        const float* gbase = eq + ((size_t)(b0 + wq) * 16 + s * 8) * DFEAT;
#pragma unroll
        for (int u = 0; u < 8; ++u) {
            const float* src = gbase + u * DFEAT + ((lane ^ u) << 2); // 16B units
            lds_u32* dst = (lds_u32*)(uintptr_t)(&X[(wq * 8 + u) * DFEAT]);
            __builtin_amdgcn_global_load_lds((glb_u32*)src, dst, 16, 0, 0);
        }
    }

    // ---- Phase 0b: envelope (independent; overlaps staging latency)
    {
        const int w = tid >> 6, k = (tid >> 3) & 7, j = tid & 7;
        const size_t rrow = ((size_t)(b0 + w) * 16 + s * 8 + j) * 12;
        const float4* rp = (const float4*)(r_ei + rrow);
        float4 ra = rp[0], rb = rp[1], rc = rp[2];
        float rr[12] = {ra.x, ra.y, ra.z, ra.w, rb.x, rb.y, rb.z, rb.w,
                        rc.x, rc.y, rc.z, rc.w};
        float e = 0.f;
#pragma unroll
        for (int a = 0; a < 4; ++a) {
            const float* Md = env_dim + ((size_t)(s * 8 + k) * 4 + a) * 9;
            float r0 = rr[a * 3], r1 = rr[a * 3 + 1], r2 = rr[a * 3 + 2];
            float e0 = r0 * Md[0] + r1 * Md[3] + r2 * Md[6];
            float e1 = r0 * Md[1] + r1 * Md[4] + r2 * Md[7];
            float e2 = r0 * Md[2] + r1 * Md[5] + r2 * Md[8];
            float dist = sqrtf(e0 * e0 + e1 * e1 + e2 * e2);
            e = fmaf(env_ion[(s * 4 + a) * 8 + k], __expf(-dist), e);
        }
        envl[w * 64 + j * 8 + k] = e;
    }

    __syncthreads(); // staging drained (vmcnt) + X visible

    // ---- Phase 1: GEMM. lane = row; un-swizzle on read.
    float4 xv[8];
    {
        const int swz = lane & 7;
#pragma unroll
        for (int j = 0; j < 8; ++j) {
            const int c16 = (wq * 8 + j) ^ swz; // 16B-chunk index within row
            xv[j] = *(const float4*)&X[lane * DFEAT + c16 * 4];
        }
    }

    float acc[16];
#pragma unroll
    for (int k = 0; k < 16; ++k) acc[k] = 0.f;

    cfp* wb1 = (cfp*)(uintptr_t)(W + s * 4096 + wq * 256);
#pragma unroll
    for (int u = 0; u < 8; ++u) {
        cfp* wr = wb1 + u * 32;
        float xs0 = xv[u].x, xs1 = xv[u].y, xs2 = xv[u].z, xs3 = xv[u].w;
#pragma unroll
        for (int c = 0; c < 4; ++c) {
            float xc = (c == 0) ? xs0 : (c == 1) ? xs1 : (c == 2) ? xs2 : xs3;
#pragma unroll
            for (int k = 0; k < 8; ++k) {
                acc[k]     = fmaf(xc, wr[c * 8 + k],        acc[k]);
                acc[8 + k] = fmaf(xc, wr[2048 + c * 8 + k], acc[8 + k]);
            }
        }
    }

    __syncthreads(); // all X reads done -> safe to alias part over X

    // ---- Phase 2a: store partials (swizzled slots keep b128 at the floor)
    {
        float* pb = part + (wq * 64 + lane) * 16;
        const int sw = (lane >> 1) & 3;
#pragma unroll
        for (int kg = 0; kg < 4; ++kg) {
            int slot = kg ^ sw;
            float4 v = make_float4(acc[kg * 4], acc[kg * 4 + 1],
                                   acc[kg * 4 + 2], acc[kg * 4 + 3]);
            *(float4*)(pb + slot * 4) = v;
        }
    }

    __syncthreads();

    // ---- Phase 2b: reduce 8 chunk-partials -> AB, fold bias into A half
    if (tid < 256) {
        const int row = tid >> 2, sl = tid & 3;
        const int g = sl ^ ((row >> 1) & 3); // true k-group held in slot sl
        float4 sum = make_float4(0.f, 0.f, 0.f, 0.f);
#pragma unroll
        for (int q2 = 0; q2 < 8; ++q2) {
            float4 v = *(const float4*)(part + (q2 * 64 + row) * 16 + sl * 4);
            sum.x += v.x; sum.y += v.y; sum.z += v.z; sum.w += v.w;
        }
        if (g < 2) {
            sum.x += bias[s * 8 + g * 4];
            sum.y += bias[s * 8 + g * 4 + 1];
            sum.z += bias[s * 8 + g * 4 + 2];
            sum.w += bias[s * 8 + g * 4 + 3];
        }
        *(float4*)(AB + row * 16 + g * 4) = sum;
    }

    __syncthreads();

    // ---- Phase 2c: one 8x8 determinant per thread, in-register LU with
    // partial pivoting; all register indices compile-time constants.
    if (tid < 64) {
        const int w = tid >> 3, i = tid & 7;
        float Arow[8];
#pragma unroll
        for (int k = 0; k < 8; ++k) Arow[k] = AB[(w * 8 + i) * 16 + k];
        float M[8][8];
#pragma unroll
        for (int j = 0; j < 8; ++j) {
#pragma unroll
            for (int k = 0; k < 8; ++k)
                M[j][k] = (Arow[k] + AB[(w * 8 + j) * 16 + 8 + k])
                          * envl[w * 64 + j * 8 + k];
        }
        float det = 1.f;
#pragma unroll
        for (int p = 0; p < 8; ++p) {
            int piv = p;
            float mx = fabsf(M[p][p]);
#pragma unroll
            for (int r2 = p + 1; r2 < 8; ++r2) {
                float v = fabsf(M[r2][p]);
                if (v > mx) { mx = v; piv = r2; }
            }
#pragma unroll
            for (int r2 = p + 1; r2 < 8; ++r2) {
                bool sw = (piv == r2);
#pragma unroll
                for (int c = p; c < 8; ++c) {
                    float a = M[p][c], bb = M[r2][c];
                    M[p][c]  = sw ? bb : a;
                    M[r2][c] = sw ? a : bb;
                }
            }
            det = (piv != p) ? -det : det;
            float d = M[p][p];
            det *= d;
            float inv = (d != 0.f) ? 1.f / d : 0.f;
#pragma unroll
            for (int r2 = p + 1; r2 < 8; ++r2) {
                float fct = M[r2][p] * inv;
#pragma unroll
                for (int c = p + 1; c < 8; ++c) M[r2][c] -= fct * M[p][c];
            }
        }
        out[(size_t)s * (BATCH * NPS) + (size_t)(b0 + w) * NPS + i] = det;
    }
}

extern "C" void kernel_launch(void* const* d_in, const int* in_sizes, int n_in,
                              void* d_out, int out_size, void* d_ws, size_t ws_size,
                              hipStream_t stream) {
    const float* eq      = (const float*)d_in[0];
    const float* r_ei    = (const float*)d_in[1];
    const float* W       = (const float*)d_in[2];
    const float* bias    = (const float*)d_in[3];
    const float* env_dim = (const float*)d_in[4];
    const float* env_ion = (const float*)d_in[5];
    float* out = (float*)d_out;

    ppdet_kernel<<<512, 512, 0, stream>>>(eq, r_ei, W, bias, env_dim, env_ion, out);
}

// Round 8
// 14.983 us; speedup vs baseline: 1.9059x; 1.0359x over previous
//
#include <hip/hip_runtime.h>
#include <stdint.h>

#define BATCH 2048
#define NPS 8
#define DFEAT 256

// Constant-address-space float: forces s_load (SMEM) codegen for uniform reads.
typedef const float __attribute__((address_space(4))) cfp;
// Address spaces for global_load_lds.
typedef __attribute__((address_space(3))) uint32_t lds_u32;
typedef const __attribute__((address_space(1))) uint32_t glb_u32;

// Block: 512 threads = 8 waves, 8 walkers x 1 spin (64 rows, 64 dets).
// X layout: [quarter q][row r][64 floats] (16KB per quarter).
// Stage: wave wq issues 8 global_load_lds (2 per quarter, strict q-order),
//        each 1KB = 4 rows' quarter, swizzled on the GLOBAL source:
//        slot p of row r holds global chunk p ^ ((r>>1)&7).
// GEMM: 4 phases gated by s_waitcnt vmcnt(6/4/2/0) + s_barrier -- staging of
//       Q1..Q3 streams underneath compute of Q0..Q2 (T3/T4 counted-vmcnt).
//       Wave wq owns f = {q*64 + wq*8 .. +8} per quarter (W wave-uniform).
// Tail: part-reduce -> AB, env (after vmcnt(0), can't disturb counts), LU.
__global__ __launch_bounds__(512) void ppdet_kernel(
    const float* __restrict__ eq,      // (B, 16, 256)
    const float* __restrict__ r_ei,    // (B, 16, 4, 3)
    const float* __restrict__ W,       // (2, 512, 8)
    const float* __restrict__ bias,    // (2, 8)
    const float* __restrict__ env_dim, // (2, 8, 4, 3, 3)
    const float* __restrict__ env_ion, // (2, 4, 8)
    float* __restrict__ out)           // (2, 2048, 8)
{
    __shared__ __align__(16) float X[4 * 64 * 64]; // 64KB, quarter-major
    __shared__ __align__(16) float AB[64 * 16];    // [row][k<8:A+bias, k>=8:Bt]
    __shared__ __align__(16) float envl[512];      // [w][j][k]
    float* part = X; // 8192 floats = X's Q0+Q1 region, disjoint from Q3 reads

    const int tid = threadIdx.x;
    const int bid = blockIdx.x;
    const int s  = bid & 1;
    const int b0 = (bid >> 1) * 8;

    const int wq   = __builtin_amdgcn_readfirstlane(tid >> 6); // 0..7, uniform
    const int lane = tid & 63;

    // ---- Stage issue: 8 DMAs per wave, strict quarter order.
    {
        const float* gw = eq + ((size_t)(b0 + wq) * 16 + s * 8) * DFEAT;
#pragma unroll
        for (int q = 0; q < 4; ++q) {
#pragma unroll
            for (int u = 0; u < 2; ++u) {
                const int r0 = wq * 8 + u * 4;       // wave-uniform row base
                const int r  = r0 + (lane >> 4);     // row this lane feeds
                const int c  = (lane & 15) ^ ((r >> 1) & 7); // src chunk swizzle
                const float* src = gw + (size_t)(r & 7) * DFEAT + q * 64 + c * 4;
                lds_u32* dst = (lds_u32*)(uintptr_t)&X[q * 4096 + r0 * 64];
                __builtin_amdgcn_global_load_lds((glb_u32*)src, dst, 16, 0, 0);
            }
            __builtin_amdgcn_sched_barrier(0); // pin issue order per quarter
        }
    }

    // ---- GEMM: 4 counted-vmcnt phases. acc persists across quarters.
    float acc[16];
#pragma unroll
    for (int k = 0; k < 16; ++k) acc[k] = 0.f;

    cfp* wbase = (cfp*)(uintptr_t)(W + s * 4096);
    const int perm = (lane >> 1) & 7;

#pragma unroll
    for (int q = 0; q < 4; ++q) {
        if (q == 0)      asm volatile("s_waitcnt vmcnt(6)" ::: "memory");
        else if (q == 1) asm volatile("s_waitcnt vmcnt(4)" ::: "memory");
        else if (q == 2) asm volatile("s_waitcnt vmcnt(2)" ::: "memory");
        else             asm volatile("s_waitcnt vmcnt(0)" ::: "memory");
        __builtin_amdgcn_s_barrier();
        __builtin_amdgcn_sched_barrier(0);

        // lane = row; un-swizzle on read (b128 at the 8-way floor).
        const float4 xa = *(const float4*)
            &X[q * 4096 + lane * 64 + (((2 * wq)     ^ perm) << 2)];
        const float4 xb = *(const float4*)
            &X[q * 4096 + lane * 64 + (((2 * wq + 1) ^ perm) << 2)];
        cfp* w1 = wbase + (q * 64 + wq * 8) * 8; // W1 rows; W2 at +2048
        const float xs[8] = {xa.x, xa.y, xa.z, xa.w, xb.x, xb.y, xb.z, xb.w};
#pragma unroll
        for (int i = 0; i < 8; ++i) {
            const float xc = xs[i];
#pragma unroll
            for (int k = 0; k < 8; ++k) {
                acc[k]     = fmaf(xc, w1[i * 8 + k],        acc[k]);
                acc[8 + k] = fmaf(xc, w1[2048 + i * 8 + k], acc[8 + k]);
            }
        }
    }

    // ---- Part-store (writes X's Q0/Q1 region; Q3 readers untouched).
    {
        float* pb = part + (wq * 64 + lane) * 16;
        const int sw = (lane >> 1) & 3;
#pragma unroll
        for (int kg = 0; kg < 4; ++kg) {
            int slot = kg ^ sw;
            float4 v = make_float4(acc[kg * 4], acc[kg * 4 + 1],
                                   acc[kg * 4 + 2], acc[kg * 4 + 3]);
            *(float4*)(pb + slot * 4) = v;
        }
    }

    // ---- Envelope (VMEM here is after vmcnt(0): counts stayed exact above).
    {
        const int w = tid >> 6, k = (tid >> 3) & 7, j = tid & 7;
        const size_t rrow = ((size_t)(b0 + w) * 16 + s * 8 + j) * 12;
        const float4* rp = (const float4*)(r_ei + rrow);
        float4 ra = rp[0], rb = rp[1], rc = rp[2];
        float rr[12] = {ra.x, ra.y, ra.z, ra.w, rb.x, rb.y, rb.z, rb.w,
                        rc.x, rc.y, rc.z, rc.w};
        float e = 0.f;
#pragma unroll
        for (int a = 0; a < 4; ++a) {
            const float* Md = env_dim + ((size_t)(s * 8 + k) * 4 + a) * 9;
            float r0 = rr[a * 3], r1 = rr[a * 3 + 1], r2 = rr[a * 3 + 2];
            float e0 = r0 * Md[0] + r1 * Md[3] + r2 * Md[6];
            float e1 = r0 * Md[1] + r1 * Md[4] + r2 * Md[7];
            float e2 = r0 * Md[2] + r1 * Md[5] + r2 * Md[8];
            float dist = sqrtf(e0 * e0 + e1 * e1 + e2 * e2);
            e = fmaf(env_ion[(s * 4 + a) * 8 + k], __expf(-dist), e);
        }
        envl[w * 64 + j * 8 + k] = e;
    }

    __syncthreads();

    // ---- Reduce 8 f-subset partials -> AB, fold bias into A half.
    if (tid < 256) {
        const int row = tid >> 2, sl = tid & 3;
        const int g = sl ^ ((row >> 1) & 3); // true k-group held in slot sl
        float4 sum = make_float4(0.f, 0.f, 0.f, 0.f);
#pragma unroll
        for (int q2 = 0; q2 < 8; ++q2) {
            float4 v = *(const float4*)(part + (q2 * 64 + row) * 16 + sl * 4);
            sum.x += v.x; sum.y += v.y; sum.z += v.z; sum.w += v.w;
        }
        if (g < 2) {
            sum.x += bias[s * 8 + g * 4];
            sum.y += bias[s * 8 + g * 4 + 1];
            sum.z += bias[s * 8 + g * 4 + 2];
            sum.w += bias[s * 8 + g * 4 + 3];
        }
        *(float4*)(AB + row * 16 + g * 4) = sum;
    }

    __syncthreads();

    // ---- One 8x8 determinant per thread, in-register LU with partial
    // pivoting; all register indices compile-time constants.
    if (tid < 64) {
        const int w = tid >> 3, i = tid & 7;
        float Arow[8];
#pragma unroll
        for (int k = 0; k < 8; ++k) Arow[k] = AB[(w * 8 + i) * 16 + k];
        float M[8][8];
#pragma unroll
        for (int j = 0; j < 8; ++j) {
#pragma unroll
            for (int k = 0; k < 8; ++k)
                M[j][k] = (Arow[k] + AB[(w * 8 + j) * 16 + 8 + k])
                          * envl[w * 64 + j * 8 + k];
        }
        float det = 1.f;
#pragma unroll
        for (int p = 0; p < 8; ++p) {
            int piv = p;
            float mx = fabsf(M[p][p]);
#pragma unroll
            for (int r2 = p + 1; r2 < 8; ++r2) {
                float v = fabsf(M[r2][p]);
                if (v > mx) { mx = v; piv = r2; }
            }
#pragma unroll
            for (int r2 = p + 1; r2 < 8; ++r2) {
                bool sw = (piv == r2);
#pragma unroll
                for (int c = p; c < 8; ++c) {
                    float a = M[p][c], bb = M[r2][c];
                    M[p][c]  = sw ? bb : a;
                    M[r2][c] = sw ? a : bb;
                }
            }
            det = (piv != p) ? -det : det;
            float d = M[p][p];
            det *= d;
            float inv = (d != 0.f) ? 1.f / d : 0.f;
#pragma unroll
            for (int r2 = p + 1; r2 < 8; ++r2) {
                float fct = M[r2][p] * inv;
#pragma unroll
                for (int c = p + 1; c < 8; ++c) M[r2][c] -= fct * M[p][c];
            }
        }
        out[(size_t)s * (BATCH * NPS) + (size_t)(b0 + w) * NPS + i] = det;
    }
}

extern "C" void kernel_launch(void* const* d_in, const int* in_sizes, int n_in,
                              void* d_out, int out_size, void* d_ws, size_t ws_size,
                              hipStream_t stream) {
    const float* eq      = (const float*)d_in[0];
    const float* r_ei    = (const float*)d_in[1];
    const float* W       = (const float*)d_in[2];
    const float* bias    = (const float*)d_in[3];
    const float* env_dim = (const float*)d_in[4];
    const float* env_ion = (const float*)d_in[5];
    float* out = (float*)d_out;

    ppdet_kernel<<<512, 512, 0, stream>>>(eq, r_ei, W, bias, env_dim, env_ion, out);
}